// Round 4
// baseline (1368.537 us; speedup 1.0000x reference)
//
#include <hip/hip_runtime.h>
#include <hip/hip_bf16.h>
#include <math.h>

// Problem constants
#define N_ROWS 16384   // B*T
#define DIM    256
#define KC     4096
#define TOPK   3
#define KSPLIT 768     // [hi|hi|lo] x [hi|lo|hi] fp16-split K
#define TOTAL_E (N_ROWS * TOPK)   // 49152
#define CHUNK 24                  // entries per wave; 49152/24 = 2048 chunks

// Output flat offsets (floats)
#define O_LOSS   0
#define O_QUANT  1
#define O_PERP   12582913
#define O_AVGP   12582914
#define O_IDX    12587010
#define O_DIST   12636162
#define O_NCS    79745026
#define O_NEMAW  79749122
#define O_UPD    80797698

typedef _Float16 h4_t __attribute__((ext_vector_type(4)));
typedef _Float16 h8_t __attribute__((ext_vector_type(8)));
typedef float    f4_t __attribute__((ext_vector_type(4)));

// async global->LDS, 16B per lane, wave-uniform LDS base + lane*16
#define GLL(g, l) __builtin_amdgcn_global_load_lds( \
    (const __attribute__((address_space(1))) unsigned int*)(g), \
    (__attribute__((address_space(3))) unsigned int*)(l), 16, 0, 0)

__device__ __forceinline__ bool vi_lt(float v, int i, float u, int j)
{
    return (v < u) || (v == u && i < j);
}

__device__ __forceinline__ void ins3(float v, int i,
    float& v0, int& i0, float& v1, int& i1, float& v2, int& i2)
{
    if (vi_lt(v, i, v2, i2)) {
        v2 = v; i2 = i;
        if (vi_lt(v2, i2, v1, i1)) { float tv=v1; int ti=i1; v1=v2; i1=i2; v2=tv; i2=ti; }
        if (vi_lt(v1, i1, v0, i0)) { float tv=v0; int ti=i0; v0=v1; i0=i1; v1=tv; i1=ti; }
    }
}

// butterfly-merge two sorted triples across lanes (XOR offset)
#define MERGE_SHFL(off) { \
    float u0=__shfl_xor(v0,off), u1=__shfl_xor(v1,off), u2=__shfl_xor(v2,off); \
    int   j0=__shfl_xor(i0,off), j1=__shfl_xor(i1,off), j2=__shfl_xor(i2,off); \
    float av[3]={v0,v1,v2}; int ai[3]={i0,i1,i2}; \
    float bv[3]={u0,u1,u2}; int bi[3]={j0,j1,j2}; \
    float rv[3]; int ri[3]; int p=0,q=0; \
    _Pragma("unroll") \
    for (int t=0;t<3;t++){ bool ta=vi_lt(av[p],ai[p],bv[q],bi[q]); \
      rv[t]=ta?av[p]:bv[q]; ri[t]=ta?ai[p]:bi[q]; p+=ta?1:0; q+=ta?0:1; } \
    v0=rv[0];v1=rv[1];v2=rv[2];i0=ri[0];i1=ri[1];i2=ri[2]; }

// ---------------------------------------------------------------- row norms
__global__ __launch_bounds__(256) void rownorm_kernel(
    const float* __restrict__ X, float* __restrict__ out, int rows)
{
    int wave = threadIdx.x >> 6;
    int lane = threadIdx.x & 63;
    int row  = blockIdx.x * 4 + wave;
    if (row >= rows) return;
    float4 v = *(const float4*)&X[(size_t)row * DIM + lane * 4];
    float s = v.x*v.x + v.y*v.y + v.z*v.z + v.w*v.w;
    #pragma unroll
    for (int off = 32; off; off >>= 1) s += __shfl_down(s, off);
    if (lane == 0) out[row] = s;
}

// -------------------------------------------- fp32 -> fp16 hi/lo split pack
// Q row layout (768): A: [hi | hi | lo]  (hi2_off=256, lo_off=512)
//                     B: [hi | lo | hi]  (hi2_off=512, lo_off=256)
__global__ __launch_bounds__(256) void convert_kernel(
    const float* __restrict__ X, _Float16* __restrict__ Q,
    int lo_off, int hi2_off)
{
    int wave = threadIdx.x >> 6;
    int lane = threadIdx.x & 63;
    int row  = blockIdx.x * 4 + wave;          // grid exact
    float4 v = *(const float4*)&X[(size_t)row * DIM + lane * 4];
    h4_t hi, lo;
    hi[0] = (_Float16)v.x; lo[0] = (_Float16)(v.x - (float)hi[0]);
    hi[1] = (_Float16)v.y; lo[1] = (_Float16)(v.y - (float)hi[1]);
    hi[2] = (_Float16)v.z; lo[2] = (_Float16)(v.z - (float)hi[2]);
    hi[3] = (_Float16)v.w; lo[3] = (_Float16)(v.w - (float)hi[3]);
    _Float16* q = Q + (size_t)row * KSPLIT + lane * 4;
    *(h4_t*)(q)           = hi;
    *(h4_t*)(q + hi2_off) = hi;
    *(h4_t*)(q + lo_off)  = lo;
}

// ------------------------------------------------- MFMA GEMM (fp16-split)
// dist[m,n] = xn[m] + en[n] - 2 * dot_f32(X[m,:], E[n,:])
// 128x128 tile, BK=64, 4 waves (2x2), 4x4 frags of 16x16x32 each.
// LDS XOR-swizzle (rule #21): linear GLL dest + inverse-permuted global
// source col-block ((l&7)^(l>>3)) + XOR'd fragment read -> 2-way banks.
// Epilogue additionally emits per-row top-3 partials of this 128-col slice.
__global__ __launch_bounds__(256) void gemm_dist_kernel(
    const _Float16* __restrict__ Aq,   // [N_ROWS, 768]
    const _Float16* __restrict__ Bq,   // [KC, 768]
    const float* __restrict__ xn,      // [N_ROWS]
    const float* __restrict__ en,      // [KC]
    float* __restrict__ dist,          // [N_ROWS, KC]
    float2* __restrict__ part)         // [N_ROWS][32][3] (val, idx-bits)
{
    __shared__ _Float16 As[128 * 64];
    __shared__ _Float16 Bs[128 * 64];

    // XCD-aware bijective swizzle: nwg=4096, 8 XCDs, 512 per chunk
    int bid = blockIdx.x;
    int swz = (bid & 7) * 512 + (bid >> 3);
    int m0 = (swz >> 5) * 128;     // 128 M-tiles
    int n0 = (swz & 31) * 128;     // 32  N-tiles

    const int tid = threadIdx.x;
    const int w = tid >> 6, l = tid & 63;
    const int wr = w >> 1, wc = w & 1;

    f4_t acc[4][4] = {};

    const int srow = l >> 3;                      // 0..7 within 8-row chunk
    const int scol = ((l & 7) ^ srow) * 8;        // inverse-swizzled source block
    const _Float16* Abase = Aq + (size_t)m0 * KSPLIT;
    const _Float16* Bbase = Bq + (size_t)n0 * KSPLIT;

    for (int kt = 0; kt < KSPLIT; kt += 64) {
        #pragma unroll
        for (int i = 0; i < 4; i++) {
            int c = w * 4 + i;            // chunk 0..15, 8 rows each
            int rg = c * 8 + srow;
            GLL(Abase + (size_t)rg * KSPLIT + kt + scol, &As[c * 512]);
            GLL(Bbase + (size_t)rg * KSPLIT + kt + scol, &Bs[c * 512]);
        }
        __syncthreads();                  // drains vmcnt before barrier

        #pragma unroll
        for (int ks = 0; ks < 2; ks++) {
            h8_t a[4], b[4];
            #pragma unroll
            for (int mf = 0; mf < 4; mf++) {
                int ra = wr*64 + mf*16 + (l & 15);
                int ho = (ks*32 + (l >> 4) * 8) ^ ((ra & 7) * 8);
                a[mf] = *(const h8_t*)&As[ra * 64 + ho];
            }
            #pragma unroll
            for (int nf = 0; nf < 4; nf++) {
                int rb = wc*64 + nf*16 + (l & 15);
                int ho = (ks*32 + (l >> 4) * 8) ^ ((rb & 7) * 8);
                b[nf] = *(const h8_t*)&Bs[rb * 64 + ho];
            }
            #pragma unroll
            for (int mf = 0; mf < 4; mf++)
                #pragma unroll
                for (int nf = 0; nf < 4; nf++)
                    acc[mf][nf] = __builtin_amdgcn_mfma_f32_16x16x32_f16(
                        a[mf], b[nf], acc[mf][nf], 0, 0, 0);
        }
        __syncthreads();
    }

    // epilogue: dist = xn + en - 2*acc, plus per-row top-3 of this slice.
    // C/D layout (m89-verified): col = lane&15, row = (lane>>4)*4 + reg
    const int cl = l & 15, rh = l >> 4;
    float ecv[4];
    #pragma unroll
    for (int nf = 0; nf < 4; nf++) ecv[nf] = en[n0 + wc*64 + nf*16 + cl];

    float2* pt = (float2*)As;   // reuse LDS: [128 rows][2 wc][3], 6 KB

    #pragma unroll
    for (int mf = 0; mf < 4; mf++) {
        int r0 = m0 + wr*64 + mf*16 + rh*4;
        float xr[4] = {xn[r0], xn[r0+1], xn[r0+2], xn[r0+3]};
        float dv[4][4];   // [nf][reg], static-indexed (fully unrolled)
        #pragma unroll
        for (int nf = 0; nf < 4; nf++) {
            int c = n0 + wc*64 + nf*16 + cl;
            float* dp = &dist[(size_t)r0 * KC + c];
            #pragma unroll
            for (int rg = 0; rg < 4; rg++) {
                float d = xr[rg] + ecv[nf] - 2.0f * acc[mf][nf][rg];
                dv[nf][rg] = d;
                dp[(size_t)KC * rg] = d;
            }
        }
        #pragma unroll
        for (int rg = 0; rg < 4; rg++) {
            float v0=INFINITY, v1=INFINITY, v2=INFINITY;
            int   i0=0x7fffffff, i1=0x7fffffff, i2=0x7fffffff;
            #pragma unroll
            for (int nf = 0; nf < 4; nf++)
                ins3(dv[nf][rg], n0 + wc*64 + nf*16 + cl, v0,i0,v1,i1,v2,i2);
            MERGE_SHFL(1); MERGE_SHFL(2); MERGE_SHFL(4); MERGE_SHFL(8);
            if (cl == 0) {
                int rl = wr*64 + mf*16 + rh*4 + rg;
                float2* q = &pt[(rl*2 + wc)*3];
                q[0] = make_float2(v0, __int_as_float(i0));
                q[1] = make_float2(v1, __int_as_float(i1));
                q[2] = make_float2(v2, __int_as_float(i2));
            }
        }
    }
    __syncthreads();
    if (tid < 128) {
        // merge the two wc-halves' sorted triples for row m0+tid
        float2 a0=pt[tid*6+0], a1=pt[tid*6+1], a2=pt[tid*6+2];
        float2 b0=pt[tid*6+3], b1=pt[tid*6+4], b2=pt[tid*6+5];
        float av[3]={a0.x,a1.x,a2.x};
        int   ai[3]={__float_as_int(a0.y),__float_as_int(a1.y),__float_as_int(a2.y)};
        float bv[3]={b0.x,b1.x,b2.x};
        int   bi[3]={__float_as_int(b0.y),__float_as_int(b1.y),__float_as_int(b2.y)};
        float rv[3]; int ri[3]; int p=0,q=0;
        #pragma unroll
        for (int t=0;t<3;t++){ bool ta=vi_lt(av[p],ai[p],bv[q],bi[q]);
            rv[t]=ta?av[p]:bv[q]; ri[t]=ta?ai[p]:bi[q]; p+=ta?1:0; q+=ta?0:1; }
        float2* dst = &part[((size_t)(m0 + tid) * 32 + (n0 >> 7)) * 3];
        dst[0] = make_float2(rv[0], __int_as_float(ri[0]));
        dst[1] = make_float2(rv[1], __int_as_float(ri[1]));
        dst[2] = make_float2(rv[2], __int_as_float(ri[2]));
    }
}

// ---------------- merge 32 per-block top-3 partials per row -> final top-3
__global__ __launch_bounds__(256) void merge_top3_kernel(
    const float2* __restrict__ part, int* __restrict__ idxw,
    float* __restrict__ out_idx, float* __restrict__ counts,
    float* __restrict__ loss_part)
{
    __shared__ float blk_loss;
    if (threadIdx.x == 0) blk_loss = 0.0f;
    __syncthreads();

    int wave = threadIdx.x >> 6;
    int lane = threadIdx.x & 63;
    int row  = blockIdx.x * 4 + wave;   // grid exact: N_ROWS/4 blocks
    const float2* pr = part + (size_t)row * 96;

    float v0=INFINITY, v1=INFINITY, v2=INFINITY;
    int   i0=0x7fffffff, i1=0x7fffffff, i2=0x7fffffff;

    float2 e0 = pr[lane];
    ins3(e0.x, __float_as_int(e0.y), v0,i0,v1,i1,v2,i2);
    if (lane < 32) {
        float2 e1 = pr[64 + lane];
        ins3(e1.x, __float_as_int(e1.y), v0,i0,v1,i1,v2,i2);
    }

    MERGE_SHFL(1); MERGE_SHFL(2); MERGE_SHFL(4);
    MERGE_SHFL(8); MERGE_SHFL(16); MERGE_SHFL(32);

    if (lane == 0) {
        int base = row * TOPK;
        idxw[base + 0] = i0; idxw[base + 1] = i1; idxw[base + 2] = i2;
        out_idx[base + 0] = (float)i0;
        out_idx[base + 1] = (float)i1;
        out_idx[base + 2] = (float)i2;
        atomicAdd(&counts[i0], 1.0f);
        atomicAdd(&counts[i1], 1.0f);
        atomicAdd(&counts[i2], 1.0f);
        atomicAdd(&blk_loss, v0 + v1 + v2);   // LDS atomic, 4/block
    }
    __syncthreads();
    if (threadIdx.x == 0) loss_part[blockIdx.x] = blk_loss;
}

// -------------------------------------------- pure gather copy: quant = E[idx]
__global__ __launch_bounds__(256) void quant_copy_kernel(
    const int* __restrict__ idxw, const float* __restrict__ E,
    float* __restrict__ quant_out)
{
    int wave = threadIdx.x >> 6;
    int lane = threadIdx.x & 63;
    int j = blockIdx.x * 4 + wave;          // 0 .. N_ROWS*TOPK-1
    int code = idxw[j];
    float4 v = *(const float4*)&E[(size_t)code * DIM + lane * 4];
    *(float4*)&quant_out[(size_t)j * DIM + lane * 4] = v;
}

// ----------------------------------------- K-wise stage 1: avg_probs, sums
__global__ __launch_bounds__(256) void kstage1_kernel(
    const float* __restrict__ counts, const float* __restrict__ ecs,
    float* __restrict__ avgp, float* __restrict__ scalars)
{
    int k = blockIdx.x * 256 + threadIdx.x;
    float cnt = counts[k];
    float pr = ecs[k] * 0.99f + 0.01f * cnt;
    float p = cnt * (1.0f / (float)N_ROWS);
    avgp[k] = p;
    float ent = p * logf(p + 1e-10f);
    int lane = threadIdx.x & 63;
    #pragma unroll
    for (int off = 32; off; off >>= 1) {
        pr  += __shfl_down(pr, off);
        ent += __shfl_down(ent, off);
    }
    if (lane == 0) {
        atomicAdd(&scalars[0], pr);
        atomicAdd(&scalars[2], ent);
    }
}

// ------------------------- K-wise stage 2: normalized new_cs (recomputes pre)
__global__ __launch_bounds__(256) void kstage2_kernel(
    const float* __restrict__ counts, const float* __restrict__ ecs,
    const float* __restrict__ scalars, float* __restrict__ ncs)
{
    int k = blockIdx.x * 256 + threadIdx.x;
    float pre = ecs[k] * 0.99f + 0.01f * counts[k];
    float nt = scalars[0];
    ncs[k] = (pre + 1e-5f) / (nt + (float)KC * 1e-5f) * nt;
}

// ----------------------------------------- prefix scan of counts -> offsets
__global__ __launch_bounds__(1024) void scan_kernel(
    const float* __restrict__ counts, int* __restrict__ offsets)
{
    __shared__ int lds[1024];
    int t = threadIdx.x;
    int c[4]; int s = 0;
    #pragma unroll
    for (int q = 0; q < 4; q++) { c[q] = (int)(counts[t * 4 + q] + 0.5f); s += c[q]; }
    lds[t] = s;
    __syncthreads();
    for (int off = 1; off < 1024; off <<= 1) {
        int v = (t >= off) ? lds[t - off] : 0;
        __syncthreads();
        lds[t] += v;
        __syncthreads();
    }
    int base = lds[t] - s;   // exclusive prefix of this thread's chunk
    offsets[t * 4 + 0] = base;
    offsets[t * 4 + 1] = base + c[0];
    offsets[t * 4 + 2] = base + c[0] + c[1];
    offsets[t * 4 + 3] = base + c[0] + c[1] + c[2];
    if (t == 1023) offsets[4096] = lds[1023];
}

// -------------------- bucket fill: packed (code<<14 | row), grouped by code
__global__ __launch_bounds__(256) void bucket_fill_kernel(
    const int* __restrict__ idxw, const int* __restrict__ offsets,
    int* __restrict__ fill, int* __restrict__ bucket_list)
{
    int j = blockIdx.x * 256 + threadIdx.x;   // grid exact
    int code = idxw[j];
    int pos = atomicAdd(&fill[code], 1);
    bucket_list[offsets[code] + pos] = (code << 14) | (j / 3);
}

// -------------- balanced gather-accumulate: dw[code] += flat[row] over chunks
__global__ __launch_bounds__(256) void codeacc_kernel(
    const int* __restrict__ bl, const float* __restrict__ flat,
    float* __restrict__ dw)
{
    int wave = threadIdx.x >> 6;
    int lane = threadIdx.x & 63;
    int chunk = blockIdx.x * 4 + wave;        // 2048 chunks, grid exact
    int beg = chunk * CHUNK;

    int ent[CHUNK];
    #pragma unroll
    for (int q = 0; q < CHUNK; q++) ent[q] = bl[beg + q];

    float4 acc = {0.0f, 0.0f, 0.0f, 0.0f};
    int prev = ent[0] >> 14;
    #pragma unroll
    for (int q = 0; q < CHUNK; q++) {
        int code = ent[q] >> 14;
        int n    = ent[q] & 0x3fff;
        if (code != prev) {
            float* p = &dw[(size_t)prev * DIM + lane * 4];
            atomicAdd(p + 0, acc.x); atomicAdd(p + 1, acc.y);
            atomicAdd(p + 2, acc.z); atomicAdd(p + 3, acc.w);
            acc.x = acc.y = acc.z = acc.w = 0.0f;
            prev = code;
        }
        float4 v = *(const float4*)&flat[(size_t)n * DIM + lane * 4];
        acc.x += v.x; acc.y += v.y; acc.z += v.z; acc.w += v.w;
    }
    float* p = &dw[(size_t)prev * DIM + lane * 4];
    atomicAdd(p + 0, acc.x); atomicAdd(p + 1, acc.y);
    atomicAdd(p + 2, acc.z); atomicAdd(p + 3, acc.w);
}

// ------------- finalize: nemaw = 0.99*emaw + 0.01*dw ; upd = nemaw / ncs
__global__ __launch_bounds__(256) void finalize_kernel(
    const float* __restrict__ dw, const float* __restrict__ emaw,
    const float* __restrict__ ncs, float* __restrict__ nemaw,
    float* __restrict__ upd)
{
    int wave = threadIdx.x >> 6;
    int lane = threadIdx.x & 63;
    int k = blockIdx.x * 4 + wave;            // 1024 blocks, grid exact
    size_t o = (size_t)k * DIM + lane * 4;
    float4 d = *(const float4*)&dw[o];
    float4 w = *(const float4*)&emaw[o];
    float4 nm;
    nm.x = 0.99f * w.x + 0.01f * d.x;
    nm.y = 0.99f * w.y + 0.01f * d.y;
    nm.z = 0.99f * w.z + 0.01f * d.z;
    nm.w = 0.99f * w.w + 0.01f * d.w;
    *(float4*)&nemaw[o] = nm;
    float inv = ncs[k];
    float4 u = {nm.x / inv, nm.y / inv, nm.z / inv, nm.w / inv};
    *(float4*)&upd[o] = u;
}

// ------------------------------------------------------------- loss reduce
__global__ __launch_bounds__(1024) void loss_reduce_kernel(
    const float* __restrict__ lp, float* __restrict__ out)
{
    __shared__ float ls[16];
    int t = threadIdx.x;
    float s = lp[t] + lp[t + 1024] + lp[t + 2048] + lp[t + 3072];
    #pragma unroll
    for (int off = 32; off; off >>= 1) s += __shfl_down(s, off);
    if ((t & 63) == 0) ls[t >> 6] = s;
    __syncthreads();
    if (t == 0) {
        float tot = 0.0f;
        #pragma unroll
        for (int i = 0; i < 16; i++) tot += ls[i];
        out[O_LOSS] = 0.25f * tot / (float)(N_ROWS * TOPK * DIM);
    }
}

// ------------------------------------------------------------- perplexity
__global__ void final_kernel(const float* __restrict__ scalars, float* __restrict__ out)
{
    out[O_PERP] = expf(-scalars[2]);
}

extern "C" void kernel_launch(void* const* d_in, const int* in_sizes, int n_in,
                              void* d_out, int out_size, void* d_ws, size_t ws_size,
                              hipStream_t stream)
{
    const float* inputs = (const float*)d_in[0];   // [16,1024,256]
    const float* emb    = (const float*)d_in[1];   // [4096,256]
    const float* ecs    = (const float*)d_in[2];   // [4096]
    const float* emaw   = (const float*)d_in[3];   // [4096,256]
    float* out = (float*)d_out;
    char* ws = (char*)d_ws;

    int*   idxw        = (int*)ws;                  // 49152 ints
    int*   bucket_list = (int*)(ws + 196608);       // 49152 ints
    float* counts      = (float*)(ws + 393216);     // 4096 f
    int*   offsets     = (int*)(ws + 409600);       // 4097 ints
    int*   fill        = (int*)(ws + 430080);       // 4096 ints
    float* xn          = (float*)(ws + 446464);     // 16384 f
    float* en          = (float*)(ws + 512000);     // 4096 f
    float* scalars     = (float*)(ws + 528384);     // 8 f
    float* loss_part   = (float*)(ws + 528448);     // 4096 f

    // Scratch in the O_QUANT output region (free until quant_copy_kernel):
    // Aq:   16384x768 f16 = 6,291,456 floats @ out+4
    // Bq:    4096x768 f16 = 1,572,864 floats @ out+6,291,464
    // dw:    4096x256 f32 = 1,048,576 floats @ out+8,000,000
    // part: 16384x32x3 float2 = 3,145,728 floats @ out+9,100,000
    //   (ends 12,245,728 < O_PERP=12,582,913)
    _Float16* Aq   = (_Float16*)(out + 4);
    _Float16* Bq   = (_Float16*)(out + 6291464);
    float*    dw   = out + 8000000;
    float2*   part = (float2*)(out + 9100000);

    hipMemsetAsync(counts, 0, KC * sizeof(float), stream);
    hipMemsetAsync(fill, 0, KC * sizeof(int), stream);
    hipMemsetAsync(scalars, 0, 8 * sizeof(float), stream);
    hipMemsetAsync(dw, 0, KC * DIM * sizeof(float), stream);

    // fp16 hi/lo split packs
    convert_kernel<<<N_ROWS / 4, 256, 0, stream>>>(inputs, Aq, 512, 256); // [hi|hi|lo]
    convert_kernel<<<KC / 4, 256, 0, stream>>>(emb, Bq, 256, 512);        // [hi|lo|hi]

    rownorm_kernel<<<N_ROWS / 4, 256, 0, stream>>>(inputs, xn, N_ROWS);
    rownorm_kernel<<<KC / 4, 256, 0, stream>>>(emb, en, KC);

    gemm_dist_kernel<<<(N_ROWS / 128) * (KC / 128), 256, 0, stream>>>(
        Aq, Bq, xn, en, out + O_DIST, part);

    merge_top3_kernel<<<N_ROWS / 4, 256, 0, stream>>>(
        part, idxw, out + O_IDX, counts, loss_part);

    kstage1_kernel<<<KC / 256, 256, 0, stream>>>(counts, ecs, out + O_AVGP, scalars);
    kstage2_kernel<<<KC / 256, 256, 0, stream>>>(counts, ecs, scalars, out + O_NCS);
    scan_kernel<<<1, 1024, 0, stream>>>(counts, offsets);
    bucket_fill_kernel<<<(N_ROWS * TOPK) / 256, 256, 0, stream>>>(
        idxw, offsets, fill, bucket_list);

    codeacc_kernel<<<(TOTAL_E / CHUNK) / 4, 256, 0, stream>>>(
        bucket_list, inputs, dw);
    finalize_kernel<<<KC / 4, 256, 0, stream>>>(
        dw, emaw, out + O_NCS, out + O_NEMAW, out + O_UPD);

    quant_copy_kernel<<<(N_ROWS * TOPK) / 4, 256, 0, stream>>>(
        idxw, emb, out + O_QUANT);

    loss_reduce_kernel<<<1, 1024, 0, stream>>>(loss_part, out);
    final_kernel<<<1, 1, 0, stream>>>(scalars, out);
}

// Round 5
// 781.151 us; speedup vs baseline: 1.7519x; 1.7519x over previous
//
#include <hip/hip_runtime.h>
#include <hip/hip_bf16.h>
#include <math.h>

// Problem constants
#define N_ROWS 16384   // B*T
#define DIM    256
#define KC     4096
#define TOPK   3
#define KSPLIT 768     // [hi|hi|lo] x [hi|lo|hi] fp16-split K
#define TOTAL_E (N_ROWS * TOPK)   // 49152
#define CHUNK 24                  // entries per wave; 49152/24 = 2048 chunks

// Output flat offsets (floats)
#define O_LOSS   0
#define O_QUANT  1
#define O_PERP   12582913
#define O_AVGP   12582914
#define O_IDX    12587010
#define O_DIST   12636162
#define O_NCS    79745026
#define O_NEMAW  79749122
#define O_UPD    80797698

typedef _Float16 h4_t __attribute__((ext_vector_type(4)));
typedef _Float16 h8_t __attribute__((ext_vector_type(8)));
typedef float    f4_t __attribute__((ext_vector_type(4)));

// async global->LDS, 16B per lane, wave-uniform LDS base + lane*16
#define GLL(g, l) __builtin_amdgcn_global_load_lds( \
    (const __attribute__((address_space(1))) unsigned int*)(g), \
    (__attribute__((address_space(3))) unsigned int*)(l), 16, 0, 0)

__device__ __forceinline__ bool vi_lt(float v, int i, float u, int j)
{
    return (v < u) || (v == u && i < j);
}

__device__ __forceinline__ void vi_min(float av, int ai, float bv, int bi,
                                       float& rv, int& ri)
{
    bool t = vi_lt(av, ai, bv, bi); rv = t ? av : bv; ri = t ? ai : bi;
}

__device__ __forceinline__ void vi_max(float av, int ai, float bv, int bi,
                                       float& rv, int& ri)
{
    bool t = vi_lt(av, ai, bv, bi); rv = t ? bv : av; ri = t ? bi : ai;
}

// merge two sorted triples -> top-3 of union. Fully static (no runtime
// array indexing -> no scratch; rule #20).
//   M0 = min(a0,b0)
//   M1 = min(a1, max(a0,b0), b1)
//   M2 = min(a2, max(a1,b0), max(a0,b1), b2)
__device__ __forceinline__ void merge3(
    float a0, int ia0, float a1, int ia1, float a2, int ia2,
    float b0, int ib0, float b1, int ib1, float b2, int ib2,
    float& r0, int& j0, float& r1, int& j1, float& r2, int& j2)
{
    float h0; int ih0;
    vi_min(a0, ia0, b0, ib0, r0, j0);
    vi_max(a0, ia0, b0, ib0, h0, ih0);
    float m1; int im1;
    vi_min(a1, ia1, b1, ib1, m1, im1);
    vi_min(m1, im1, h0, ih0, r1, j1);
    float x1, y1; int ix1, iy1;
    vi_max(a1, ia1, b0, ib0, x1, ix1);
    vi_max(a0, ia0, b1, ib1, y1, iy1);
    float m2; int im2;
    vi_min(a2, ia2, b2, ib2, m2, im2);
    float m3; int im3;
    vi_min(x1, ix1, y1, iy1, m3, im3);
    vi_min(m2, im2, m3, im3, r2, j2);
}

__device__ __forceinline__ void ins3(float v, int i,
    float& v0, int& i0, float& v1, int& i1, float& v2, int& i2)
{
    if (vi_lt(v, i, v2, i2)) {
        v2 = v; i2 = i;
        if (vi_lt(v2, i2, v1, i1)) { float tv=v1; int ti=i1; v1=v2; i1=i2; v2=tv; i2=ti; }
        if (vi_lt(v1, i1, v0, i0)) { float tv=v0; int ti=i0; v0=v1; i0=i1; v1=tv; i1=ti; }
    }
}

// butterfly-merge sorted triples across lanes (XOR offset), scratch-free
#define MERGE_SHFL(off) { \
    float u0=__shfl_xor(v0,off), u1=__shfl_xor(v1,off), u2=__shfl_xor(v2,off); \
    int   j0s=__shfl_xor(i0,off), j1s=__shfl_xor(i1,off), j2s=__shfl_xor(i2,off); \
    float nv0,nv1,nv2; int ni0,ni1,ni2; \
    merge3(v0,i0,v1,i1,v2,i2, u0,j0s,u1,j1s,u2,j2s, nv0,ni0,nv1,ni1,nv2,ni2); \
    v0=nv0;v1=nv1;v2=nv2;i0=ni0;i1=ni1;i2=ni2; }

// ---------------------------------------------------------------- row norms
__global__ __launch_bounds__(256) void rownorm_kernel(
    const float* __restrict__ X, float* __restrict__ out, int rows)
{
    int wave = threadIdx.x >> 6;
    int lane = threadIdx.x & 63;
    int row  = blockIdx.x * 4 + wave;
    if (row >= rows) return;
    float4 v = *(const float4*)&X[(size_t)row * DIM + lane * 4];
    float s = v.x*v.x + v.y*v.y + v.z*v.z + v.w*v.w;
    #pragma unroll
    for (int off = 32; off; off >>= 1) s += __shfl_down(s, off);
    if (lane == 0) out[row] = s;
}

// -------------------------------------------- fp32 -> fp16 hi/lo split pack
// Q row layout (768): A: [hi | hi | lo]  (hi2_off=256, lo_off=512)
//                     B: [hi | lo | hi]  (hi2_off=512, lo_off=256)
__global__ __launch_bounds__(256) void convert_kernel(
    const float* __restrict__ X, _Float16* __restrict__ Q,
    int lo_off, int hi2_off)
{
    int wave = threadIdx.x >> 6;
    int lane = threadIdx.x & 63;
    int row  = blockIdx.x * 4 + wave;          // grid exact
    float4 v = *(const float4*)&X[(size_t)row * DIM + lane * 4];
    h4_t hi, lo;
    hi[0] = (_Float16)v.x; lo[0] = (_Float16)(v.x - (float)hi[0]);
    hi[1] = (_Float16)v.y; lo[1] = (_Float16)(v.y - (float)hi[1]);
    hi[2] = (_Float16)v.z; lo[2] = (_Float16)(v.z - (float)hi[2]);
    hi[3] = (_Float16)v.w; lo[3] = (_Float16)(v.w - (float)hi[3]);
    _Float16* q = Q + (size_t)row * KSPLIT + lane * 4;
    *(h4_t*)(q)           = hi;
    *(h4_t*)(q + hi2_off) = hi;
    *(h4_t*)(q + lo_off)  = lo;
}

// ------------------------------------------------- MFMA GEMM (fp16-split)
// dist[m,n] = xn[m] + en[n] - 2 * dot_f32(X[m,:], E[n,:])
// 128x128 tile, BK=64, 4 waves (2x2), 4x4 frags of 16x16x32 each.
// Main loop is the round-3-proven LINEAR layout (swizzle reverted).
// Epilogue additionally emits per-row top-3 partials of this 128-col slice
// via a fully-static merge network (no scratch).
__global__ __launch_bounds__(256) void gemm_dist_kernel(
    const _Float16* __restrict__ Aq,   // [N_ROWS, 768]
    const _Float16* __restrict__ Bq,   // [KC, 768]
    const float* __restrict__ xn,      // [N_ROWS]
    const float* __restrict__ en,      // [KC]
    float* __restrict__ dist,          // [N_ROWS, KC]
    float2* __restrict__ part)         // [N_ROWS][32][3] (val, idx-bits)
{
    __shared__ _Float16 As[128 * 64];
    __shared__ _Float16 Bs[128 * 64];

    // XCD-aware bijective swizzle: nwg=4096, 8 XCDs, 512 per chunk
    int bid = blockIdx.x;
    int swz = (bid & 7) * 512 + (bid >> 3);
    int m0 = (swz >> 5) * 128;     // 128 M-tiles
    int n0 = (swz & 31) * 128;     // 32  N-tiles

    const int tid = threadIdx.x;
    const int w = tid >> 6, l = tid & 63;
    const int wr = w >> 1, wc = w & 1;

    f4_t acc[4][4] = {};

    const int srow = l >> 3;              // 0..7 within 8-row chunk
    const int scol = (l & 7) * 8;         // LINEAR source block (round-3)
    const _Float16* Abase = Aq + (size_t)m0 * KSPLIT;
    const _Float16* Bbase = Bq + (size_t)n0 * KSPLIT;

    for (int kt = 0; kt < KSPLIT; kt += 64) {
        #pragma unroll
        for (int i = 0; i < 4; i++) {
            int c = w * 4 + i;            // chunk 0..15, 8 rows each
            int rg = c * 8 + srow;
            GLL(Abase + (size_t)rg * KSPLIT + kt + scol, &As[c * 512]);
            GLL(Bbase + (size_t)rg * KSPLIT + kt + scol, &Bs[c * 512]);
        }
        __syncthreads();                  // drains vmcnt before barrier

        #pragma unroll
        for (int ks = 0; ks < 2; ks++) {
            h8_t a[4], b[4];
            #pragma unroll
            for (int mf = 0; mf < 4; mf++)
                a[mf] = *(const h8_t*)&As[(wr*64 + mf*16 + (l & 15)) * 64 + ks*32 + (l >> 4) * 8];
            #pragma unroll
            for (int nf = 0; nf < 4; nf++)
                b[nf] = *(const h8_t*)&Bs[(wc*64 + nf*16 + (l & 15)) * 64 + ks*32 + (l >> 4) * 8];
            #pragma unroll
            for (int mf = 0; mf < 4; mf++)
                #pragma unroll
                for (int nf = 0; nf < 4; nf++)
                    acc[mf][nf] = __builtin_amdgcn_mfma_f32_16x16x32_f16(
                        a[mf], b[nf], acc[mf][nf], 0, 0, 0);
        }
        __syncthreads();
    }

    // epilogue: dist = xn + en - 2*acc, plus per-row top-3 of this slice.
    // C/D layout (m89-verified): col = lane&15, row = (lane>>4)*4 + reg
    const int cl = l & 15, rh = l >> 4;
    float ecv[4];
    #pragma unroll
    for (int nf = 0; nf < 4; nf++) ecv[nf] = en[n0 + wc*64 + nf*16 + cl];

    float2* pt = (float2*)As;   // reuse LDS: [128 rows][2 wc][3], 6 KB

    #pragma unroll
    for (int mf = 0; mf < 4; mf++) {
        int r0 = m0 + wr*64 + mf*16 + rh*4;
        float xr[4] = {xn[r0], xn[r0+1], xn[r0+2], xn[r0+3]};
        float dv[4][4];   // [nf][reg], static-indexed (fully unrolled)
        #pragma unroll
        for (int nf = 0; nf < 4; nf++) {
            int c = n0 + wc*64 + nf*16 + cl;
            float* dp = &dist[(size_t)r0 * KC + c];
            #pragma unroll
            for (int rg = 0; rg < 4; rg++) {
                float d = xr[rg] + ecv[nf] - 2.0f * acc[mf][nf][rg];
                dv[nf][rg] = d;
                dp[(size_t)KC * rg] = d;
            }
        }
        #pragma unroll
        for (int rg = 0; rg < 4; rg++) {
            float v0=INFINITY, v1=INFINITY, v2=INFINITY;
            int   i0=0x7fffffff, i1=0x7fffffff, i2=0x7fffffff;
            #pragma unroll
            for (int nf = 0; nf < 4; nf++)
                ins3(dv[nf][rg], n0 + wc*64 + nf*16 + cl, v0,i0,v1,i1,v2,i2);
            MERGE_SHFL(1); MERGE_SHFL(2); MERGE_SHFL(4); MERGE_SHFL(8);
            if (cl == 0) {
                int rl = wr*64 + mf*16 + rh*4 + rg;
                float2* q = &pt[(rl*2 + wc)*3];
                q[0] = make_float2(v0, __int_as_float(i0));
                q[1] = make_float2(v1, __int_as_float(i1));
                q[2] = make_float2(v2, __int_as_float(i2));
            }
        }
    }
    __syncthreads();
    if (tid < 128) {
        // merge the two wc-halves' sorted triples for row m0+tid
        float2 a0=pt[tid*6+0], a1=pt[tid*6+1], a2=pt[tid*6+2];
        float2 b0=pt[tid*6+3], b1=pt[tid*6+4], b2=pt[tid*6+5];
        float rv0, rv1, rv2; int ri0, ri1, ri2;
        merge3(a0.x, __float_as_int(a0.y), a1.x, __float_as_int(a1.y),
               a2.x, __float_as_int(a2.y),
               b0.x, __float_as_int(b0.y), b1.x, __float_as_int(b1.y),
               b2.x, __float_as_int(b2.y),
               rv0, ri0, rv1, ri1, rv2, ri2);
        float2* dst = &part[((size_t)(m0 + tid) * 32 + (n0 >> 7)) * 3];
        dst[0] = make_float2(rv0, __int_as_float(ri0));
        dst[1] = make_float2(rv1, __int_as_float(ri1));
        dst[2] = make_float2(rv2, __int_as_float(ri2));
    }
}

// ---------------- merge 32 per-block top-3 partials per row -> final top-3
__global__ __launch_bounds__(256) void merge_top3_kernel(
    const float2* __restrict__ part, int* __restrict__ idxw,
    float* __restrict__ out_idx, float* __restrict__ counts,
    float* __restrict__ loss_part)
{
    __shared__ float blk_loss;
    if (threadIdx.x == 0) blk_loss = 0.0f;
    __syncthreads();

    int wave = threadIdx.x >> 6;
    int lane = threadIdx.x & 63;
    int row  = blockIdx.x * 4 + wave;   // grid exact: N_ROWS/4 blocks
    const float2* pr = part + (size_t)row * 96;

    float v0=INFINITY, v1=INFINITY, v2=INFINITY;
    int   i0=0x7fffffff, i1=0x7fffffff, i2=0x7fffffff;

    float2 e0 = pr[lane];
    ins3(e0.x, __float_as_int(e0.y), v0,i0,v1,i1,v2,i2);
    if (lane < 32) {
        float2 e1 = pr[64 + lane];
        ins3(e1.x, __float_as_int(e1.y), v0,i0,v1,i1,v2,i2);
    }

    MERGE_SHFL(1); MERGE_SHFL(2); MERGE_SHFL(4);
    MERGE_SHFL(8); MERGE_SHFL(16); MERGE_SHFL(32);

    if (lane == 0) {
        int base = row * TOPK;
        idxw[base + 0] = i0; idxw[base + 1] = i1; idxw[base + 2] = i2;
        out_idx[base + 0] = (float)i0;
        out_idx[base + 1] = (float)i1;
        out_idx[base + 2] = (float)i2;
        atomicAdd(&counts[i0], 1.0f);
        atomicAdd(&counts[i1], 1.0f);
        atomicAdd(&counts[i2], 1.0f);
        atomicAdd(&blk_loss, v0 + v1 + v2);   // LDS atomic, 4/block
    }
    __syncthreads();
    if (threadIdx.x == 0) loss_part[blockIdx.x] = blk_loss;
}

// -------------------------------------------- pure gather copy: quant = E[idx]
__global__ __launch_bounds__(256) void quant_copy_kernel(
    const int* __restrict__ idxw, const float* __restrict__ E,
    float* __restrict__ quant_out)
{
    int wave = threadIdx.x >> 6;
    int lane = threadIdx.x & 63;
    int j = blockIdx.x * 4 + wave;          // 0 .. N_ROWS*TOPK-1
    int code = idxw[j];
    float4 v = *(const float4*)&E[(size_t)code * DIM + lane * 4];
    *(float4*)&quant_out[(size_t)j * DIM + lane * 4] = v;
}

// ----------------------------------------- K-wise stage 1: avg_probs, sums
__global__ __launch_bounds__(256) void kstage1_kernel(
    const float* __restrict__ counts, const float* __restrict__ ecs,
    float* __restrict__ avgp, float* __restrict__ scalars)
{
    int k = blockIdx.x * 256 + threadIdx.x;
    float cnt = counts[k];
    float pr = ecs[k] * 0.99f + 0.01f * cnt;
    float p = cnt * (1.0f / (float)N_ROWS);
    avgp[k] = p;
    float ent = p * logf(p + 1e-10f);
    int lane = threadIdx.x & 63;
    #pragma unroll
    for (int off = 32; off; off >>= 1) {
        pr  += __shfl_down(pr, off);
        ent += __shfl_down(ent, off);
    }
    if (lane == 0) {
        atomicAdd(&scalars[0], pr);
        atomicAdd(&scalars[2], ent);
    }
}

// ------------------------- K-wise stage 2: normalized new_cs (recomputes pre)
__global__ __launch_bounds__(256) void kstage2_kernel(
    const float* __restrict__ counts, const float* __restrict__ ecs,
    const float* __restrict__ scalars, float* __restrict__ ncs)
{
    int k = blockIdx.x * 256 + threadIdx.x;
    float pre = ecs[k] * 0.99f + 0.01f * counts[k];
    float nt = scalars[0];
    ncs[k] = (pre + 1e-5f) / (nt + (float)KC * 1e-5f) * nt;
}

// ----------------------------------------- prefix scan of counts -> offsets
__global__ __launch_bounds__(1024) void scan_kernel(
    const float* __restrict__ counts, int* __restrict__ offsets)
{
    __shared__ int lds[1024];
    int t = threadIdx.x;
    int c[4]; int s = 0;
    #pragma unroll
    for (int q = 0; q < 4; q++) { c[q] = (int)(counts[t * 4 + q] + 0.5f); s += c[q]; }
    lds[t] = s;
    __syncthreads();
    for (int off = 1; off < 1024; off <<= 1) {
        int v = (t >= off) ? lds[t - off] : 0;
        __syncthreads();
        lds[t] += v;
        __syncthreads();
    }
    int base = lds[t] - s;   // exclusive prefix of this thread's chunk
    offsets[t * 4 + 0] = base;
    offsets[t * 4 + 1] = base + c[0];
    offsets[t * 4 + 2] = base + c[0] + c[1];
    offsets[t * 4 + 3] = base + c[0] + c[1] + c[2];
    if (t == 1023) offsets[4096] = lds[1023];
}

// -------------------- bucket fill: packed (code<<14 | row), grouped by code
__global__ __launch_bounds__(256) void bucket_fill_kernel(
    const int* __restrict__ idxw, const int* __restrict__ offsets,
    int* __restrict__ fill, int* __restrict__ bucket_list)
{
    int j = blockIdx.x * 256 + threadIdx.x;   // grid exact
    int code = idxw[j];
    int pos = atomicAdd(&fill[code], 1);
    bucket_list[offsets[code] + pos] = (code << 14) | (j / 3);
}

// -------------- balanced gather-accumulate: dw[code] += flat[row] over chunks
__global__ __launch_bounds__(256) void codeacc_kernel(
    const int* __restrict__ bl, const float* __restrict__ flat,
    float* __restrict__ dw)
{
    int wave = threadIdx.x >> 6;
    int lane = threadIdx.x & 63;
    int chunk = blockIdx.x * 4 + wave;        // 2048 chunks, grid exact
    int beg = chunk * CHUNK;

    int ent[CHUNK];
    #pragma unroll
    for (int q = 0; q < CHUNK; q++) ent[q] = bl[beg + q];

    float4 acc = {0.0f, 0.0f, 0.0f, 0.0f};
    int prev = ent[0] >> 14;
    #pragma unroll
    for (int q = 0; q < CHUNK; q++) {
        int code = ent[q] >> 14;
        int n    = ent[q] & 0x3fff;
        if (code != prev) {
            float* p = &dw[(size_t)prev * DIM + lane * 4];
            atomicAdd(p + 0, acc.x); atomicAdd(p + 1, acc.y);
            atomicAdd(p + 2, acc.z); atomicAdd(p + 3, acc.w);
            acc.x = acc.y = acc.z = acc.w = 0.0f;
            prev = code;
        }
        float4 v = *(const float4*)&flat[(size_t)n * DIM + lane * 4];
        acc.x += v.x; acc.y += v.y; acc.z += v.z; acc.w += v.w;
    }
    float* p = &dw[(size_t)prev * DIM + lane * 4];
    atomicAdd(p + 0, acc.x); atomicAdd(p + 1, acc.y);
    atomicAdd(p + 2, acc.z); atomicAdd(p + 3, acc.w);
}

// ------------- finalize: nemaw = 0.99*emaw + 0.01*dw ; upd = nemaw / ncs
__global__ __launch_bounds__(256) void finalize_kernel(
    const float* __restrict__ dw, const float* __restrict__ emaw,
    const float* __restrict__ ncs, float* __restrict__ nemaw,
    float* __restrict__ upd)
{
    int wave = threadIdx.x >> 6;
    int lane = threadIdx.x & 63;
    int k = blockIdx.x * 4 + wave;            // 1024 blocks, grid exact
    size_t o = (size_t)k * DIM + lane * 4;
    float4 d = *(const float4*)&dw[o];
    float4 w = *(const float4*)&emaw[o];
    float4 nm;
    nm.x = 0.99f * w.x + 0.01f * d.x;
    nm.y = 0.99f * w.y + 0.01f * d.y;
    nm.z = 0.99f * w.z + 0.01f * d.z;
    nm.w = 0.99f * w.w + 0.01f * d.w;
    *(float4*)&nemaw[o] = nm;
    float inv = ncs[k];
    float4 u = {nm.x / inv, nm.y / inv, nm.z / inv, nm.w / inv};
    *(float4*)&upd[o] = u;
}

// ------------------------------------------------------------- loss reduce
__global__ __launch_bounds__(1024) void loss_reduce_kernel(
    const float* __restrict__ lp, float* __restrict__ out)
{
    __shared__ float ls[16];
    int t = threadIdx.x;
    float s = lp[t] + lp[t + 1024] + lp[t + 2048] + lp[t + 3072];
    #pragma unroll
    for (int off = 32; off; off >>= 1) s += __shfl_down(s, off);
    if ((t & 63) == 0) ls[t >> 6] = s;
    __syncthreads();
    if (t == 0) {
        float tot = 0.0f;
        #pragma unroll
        for (int i = 0; i < 16; i++) tot += ls[i];
        out[O_LOSS] = 0.25f * tot / (float)(N_ROWS * TOPK * DIM);
    }
}

// ------------------------------------------------------------- perplexity
__global__ void final_kernel(const float* __restrict__ scalars, float* __restrict__ out)
{
    out[O_PERP] = expf(-scalars[2]);
}

extern "C" void kernel_launch(void* const* d_in, const int* in_sizes, int n_in,
                              void* d_out, int out_size, void* d_ws, size_t ws_size,
                              hipStream_t stream)
{
    const float* inputs = (const float*)d_in[0];   // [16,1024,256]
    const float* emb    = (const float*)d_in[1];   // [4096,256]
    const float* ecs    = (const float*)d_in[2];   // [4096]
    const float* emaw   = (const float*)d_in[3];   // [4096,256]
    float* out = (float*)d_out;
    char* ws = (char*)d_ws;

    int*   idxw        = (int*)ws;                  // 49152 ints
    int*   bucket_list = (int*)(ws + 196608);       // 49152 ints
    float* counts      = (float*)(ws + 393216);     // 4096 f
    int*   offsets     = (int*)(ws + 409600);       // 4097 ints
    int*   fill        = (int*)(ws + 430080);       // 4096 ints
    float* xn          = (float*)(ws + 446464);     // 16384 f
    float* en          = (float*)(ws + 512000);     // 4096 f
    float* scalars     = (float*)(ws + 528384);     // 8 f
    float* loss_part   = (float*)(ws + 528448);     // 4096 f

    // Scratch in the O_QUANT output region (free until quant_copy_kernel):
    // Aq:   16384x768 f16 = 6,291,456 floats @ out+4
    // Bq:    4096x768 f16 = 1,572,864 floats @ out+6,291,464
    // dw:    4096x256 f32 = 1,048,576 floats @ out+8,000,000
    // part: 16384x32x3 float2 = 3,145,728 floats @ out+9,100,000
    //   (ends 12,245,728 < O_PERP=12,582,913)
    _Float16* Aq   = (_Float16*)(out + 4);
    _Float16* Bq   = (_Float16*)(out + 6291464);
    float*    dw   = out + 8000000;
    float2*   part = (float2*)(out + 9100000);

    hipMemsetAsync(counts, 0, KC * sizeof(float), stream);
    hipMemsetAsync(fill, 0, KC * sizeof(int), stream);
    hipMemsetAsync(scalars, 0, 8 * sizeof(float), stream);
    hipMemsetAsync(dw, 0, KC * DIM * sizeof(float), stream);

    // fp16 hi/lo split packs
    convert_kernel<<<N_ROWS / 4, 256, 0, stream>>>(inputs, Aq, 512, 256); // [hi|hi|lo]
    convert_kernel<<<KC / 4, 256, 0, stream>>>(emb, Bq, 256, 512);        // [hi|lo|hi]

    rownorm_kernel<<<N_ROWS / 4, 256, 0, stream>>>(inputs, xn, N_ROWS);
    rownorm_kernel<<<KC / 4, 256, 0, stream>>>(emb, en, KC);

    gemm_dist_kernel<<<(N_ROWS / 128) * (KC / 128), 256, 0, stream>>>(
        Aq, Bq, xn, en, out + O_DIST, part);

    merge_top3_kernel<<<N_ROWS / 4, 256, 0, stream>>>(
        part, idxw, out + O_IDX, counts, loss_part);

    kstage1_kernel<<<KC / 256, 256, 0, stream>>>(counts, ecs, out + O_AVGP, scalars);
    kstage2_kernel<<<KC / 256, 256, 0, stream>>>(counts, ecs, scalars, out + O_NCS);
    scan_kernel<<<1, 1024, 0, stream>>>(counts, offsets);
    bucket_fill_kernel<<<(N_ROWS * TOPK) / 256, 256, 0, stream>>>(
        idxw, offsets, fill, bucket_list);

    codeacc_kernel<<<(TOTAL_E / CHUNK) / 4, 256, 0, stream>>>(
        bucket_list, inputs, dw);
    finalize_kernel<<<KC / 4, 256, 0, stream>>>(
        dw, emaw, out + O_NCS, out + O_NEMAW, out + O_UPD);

    quant_copy_kernel<<<(N_ROWS * TOPK) / 4, 256, 0, stream>>>(
        idxw, emb, out + O_QUANT);

    loss_reduce_kernel<<<1, 1024, 0, stream>>>(loss_part, out);
    final_kernel<<<1, 1, 0, stream>>>(scalars, out);
}

// Round 6
// 710.873 us; speedup vs baseline: 1.9252x; 1.0989x over previous
//
#include <hip/hip_runtime.h>
#include <hip/hip_bf16.h>
#include <math.h>

// Problem constants
#define N_ROWS 16384   // B*T
#define DIM    256
#define KC     4096
#define TOPK   3
#define KSPLIT 768     // [hi|hi|lo] x [hi|lo|hi] fp16-split K
#define TOTAL_E (N_ROWS * TOPK)   // 49152
#define CHUNK 24                  // entries per wave; 49152/24 = 2048 chunks

// Output flat offsets (floats)
#define O_LOSS   0
#define O_QUANT  1
#define O_PERP   12582913
#define O_AVGP   12582914
#define O_IDX    12587010
#define O_DIST   12636162
#define O_NCS    79745026
#define O_NEMAW  79749122
#define O_UPD    80797698

typedef _Float16 h4_t __attribute__((ext_vector_type(4)));
typedef _Float16 h8_t __attribute__((ext_vector_type(8)));
typedef float    f4_t __attribute__((ext_vector_type(4)));

// async global->LDS, 16B per lane, wave-uniform LDS base + lane*16
#define GLL(g, l) __builtin_amdgcn_global_load_lds( \
    (const __attribute__((address_space(1))) unsigned int*)(g), \
    (__attribute__((address_space(3))) unsigned int*)(l), 16, 0, 0)

// ---------------------------------------------------------------- row norms
__global__ __launch_bounds__(256) void rownorm_kernel(
    const float* __restrict__ X, float* __restrict__ out, int rows)
{
    int wave = threadIdx.x >> 6;
    int lane = threadIdx.x & 63;
    int row  = blockIdx.x * 4 + wave;
    if (row >= rows) return;
    float4 v = *(const float4*)&X[(size_t)row * DIM + lane * 4];
    float s = v.x*v.x + v.y*v.y + v.z*v.z + v.w*v.w;
    #pragma unroll
    for (int off = 32; off; off >>= 1) s += __shfl_down(s, off);
    if (lane == 0) out[row] = s;
}

// -------------------------------------------- fp32 -> fp16 hi/lo split pack
// Q row layout (768): A: [hi | hi | lo]  (hi2_off=256, lo_off=512)
//                     B: [hi | lo | hi]  (hi2_off=512, lo_off=256)
__global__ __launch_bounds__(256) void convert_kernel(
    const float* __restrict__ X, _Float16* __restrict__ Q,
    int lo_off, int hi2_off)
{
    int wave = threadIdx.x >> 6;
    int lane = threadIdx.x & 63;
    int row  = blockIdx.x * 4 + wave;          // grid exact
    float4 v = *(const float4*)&X[(size_t)row * DIM + lane * 4];
    h4_t hi, lo;
    hi[0] = (_Float16)v.x; lo[0] = (_Float16)(v.x - (float)hi[0]);
    hi[1] = (_Float16)v.y; lo[1] = (_Float16)(v.y - (float)hi[1]);
    hi[2] = (_Float16)v.z; lo[2] = (_Float16)(v.z - (float)hi[2]);
    hi[3] = (_Float16)v.w; lo[3] = (_Float16)(v.w - (float)hi[3]);
    _Float16* q = Q + (size_t)row * KSPLIT + lane * 4;
    *(h4_t*)(q)           = hi;
    *(h4_t*)(q + hi2_off) = hi;
    *(h4_t*)(q + lo_off)  = lo;
}

// ------------------------------------------------- MFMA GEMM (fp16-split)
// dist[m,n] = xn[m] + en[n] - 2 * dot_f32(X[m,:], E[n,:])
// 128x128 tile, BK=64, 4 waves (2x2), 4x4 frags of 16x16x32 each.
// LDS XOR-swizzle (rule #21, both-sides): GLL dest stays linear; the GLOBAL
// source 16B-block is pre-permuted by b ^= (row&7), and the fragment read
// XORs the same involution back. Data is bit-identical to the linear
// version; ds_read bank conflicts drop 16-way -> ~0 (verified round 4).
__global__ __launch_bounds__(256) void gemm_dist_kernel(
    const _Float16* __restrict__ Aq,   // [N_ROWS, 768]
    const _Float16* __restrict__ Bq,   // [KC, 768]
    const float* __restrict__ xn,      // [N_ROWS]
    const float* __restrict__ en,      // [KC]
    float* __restrict__ dist)          // [N_ROWS, KC]
{
    __shared__ _Float16 As[128 * 64];
    __shared__ _Float16 Bs[128 * 64];

    // XCD-aware bijective swizzle: nwg=4096, 8 XCDs, 512 per chunk
    int bid = blockIdx.x;
    int swz = (bid & 7) * 512 + (bid >> 3);
    int m0 = (swz >> 5) * 128;     // 128 M-tiles
    int n0 = (swz & 31) * 128;     // 32  N-tiles

    const int tid = threadIdx.x;
    const int w = tid >> 6, l = tid & 63;
    const int wr = w >> 1, wc = w & 1;

    f4_t acc[4][4] = {};

    const int srow = l >> 3;                      // 0..7 within 8-row chunk
    const int scol = ((l & 7) ^ srow) * 8;        // inverse-swizzled source block
    const _Float16* Abase = Aq + (size_t)m0 * KSPLIT;
    const _Float16* Bbase = Bq + (size_t)n0 * KSPLIT;

    for (int kt = 0; kt < KSPLIT; kt += 64) {
        #pragma unroll
        for (int i = 0; i < 4; i++) {
            int c = w * 4 + i;            // chunk 0..15, 8 rows each
            int rg = c * 8 + srow;
            GLL(Abase + (size_t)rg * KSPLIT + kt + scol, &As[c * 512]);
            GLL(Bbase + (size_t)rg * KSPLIT + kt + scol, &Bs[c * 512]);
        }
        __syncthreads();                  // drains vmcnt before barrier

        #pragma unroll
        for (int ks = 0; ks < 2; ks++) {
            h8_t a[4], b[4];
            #pragma unroll
            for (int mf = 0; mf < 4; mf++) {
                int ra = wr*64 + mf*16 + (l & 15);
                int ho = (ks*32 + (l >> 4) * 8) ^ ((ra & 7) * 8);
                a[mf] = *(const h8_t*)&As[ra * 64 + ho];
            }
            #pragma unroll
            for (int nf = 0; nf < 4; nf++) {
                int rb = wc*64 + nf*16 + (l & 15);
                int ho = (ks*32 + (l >> 4) * 8) ^ ((rb & 7) * 8);
                b[nf] = *(const h8_t*)&Bs[rb * 64 + ho];
            }
            #pragma unroll
            for (int mf = 0; mf < 4; mf++)
                #pragma unroll
                for (int nf = 0; nf < 4; nf++)
                    acc[mf][nf] = __builtin_amdgcn_mfma_f32_16x16x32_f16(
                        a[mf], b[nf], acc[mf][nf], 0, 0, 0);
        }
        __syncthreads();
    }

    // epilogue: dist = xn + en - 2*acc
    // C/D layout (m89-verified): col = lane&15, row = (lane>>4)*4 + reg
    const int cl = l & 15, rh = l >> 4;
    float ecv[4];
    #pragma unroll
    for (int nf = 0; nf < 4; nf++) ecv[nf] = en[n0 + wc*64 + nf*16 + cl];

    #pragma unroll
    for (int mf = 0; mf < 4; mf++) {
        int r0 = m0 + wr*64 + mf*16 + rh*4;
        float x0 = xn[r0], x1 = xn[r0+1], x2 = xn[r0+2], x3 = xn[r0+3];
        #pragma unroll
        for (int nf = 0; nf < 4; nf++) {
            int c = n0 + wc*64 + nf*16 + cl;
            float* dp = &dist[(size_t)r0 * KC + c];
            dp[0]           = x0 + ecv[nf] - 2.0f * acc[mf][nf][0];
            dp[(size_t)KC]  = x1 + ecv[nf] - 2.0f * acc[mf][nf][1];
            dp[(size_t)KC*2]= x2 + ecv[nf] - 2.0f * acc[mf][nf][2];
            dp[(size_t)KC*3]= x3 + ecv[nf] - 2.0f * acc[mf][nf][3];
        }
    }
}

// ---------------------------------------------------------------- top-3
__device__ __forceinline__ bool vi_lt(float v, int i, float u, int j)
{
    return (v < u) || (v == u && i < j);
}

// one wave per row; accumulates the commitment-loss partial per block
__global__ __launch_bounds__(256) void top3_kernel(
    const float* __restrict__ dist, int* __restrict__ idxw,
    float* __restrict__ out_idx, float* __restrict__ counts,
    float* __restrict__ loss_part)
{
    __shared__ float blk_loss;
    if (threadIdx.x == 0) blk_loss = 0.0f;
    __syncthreads();

    int wave = threadIdx.x >> 6;
    int lane = threadIdx.x & 63;
    int row  = blockIdx.x * 4 + wave;   // grid exact: N_ROWS/4 blocks
    const float* dr = dist + (size_t)row * KC;

    float v0 = INFINITY, v1 = INFINITY, v2 = INFINITY;
    int   i0 = 0x7fffffff, i1 = 0x7fffffff, i2 = 0x7fffffff;

    #pragma unroll 4
    for (int it = 0; it < 16; it++) {
        int c = (it * 64 + lane) * 4;
        float4 d = *(const float4*)&dr[c];
        float dv[4] = {d.x, d.y, d.z, d.w};
        #pragma unroll
        for (int q = 0; q < 4; q++) {
            float v = dv[q]; int ci = c + q;
            if (vi_lt(v, ci, v2, i2)) {
                v2 = v; i2 = ci;
                if (vi_lt(v2, i2, v1, i1)) { float tv = v1; int ti = i1; v1 = v2; i1 = i2; v2 = tv; i2 = ti; }
                if (vi_lt(v1, i1, v0, i0)) { float tv = v0; int ti = i0; v0 = v1; i0 = i1; v1 = tv; i1 = ti; }
            }
        }
    }

    #pragma unroll
    for (int off = 1; off < 64; off <<= 1) {
        float u0 = __shfl_xor(v0, off), u1 = __shfl_xor(v1, off), u2 = __shfl_xor(v2, off);
        int   j0 = __shfl_xor(i0, off), j1 = __shfl_xor(i1, off), j2 = __shfl_xor(i2, off);
        float av[3] = {v0, v1, v2}; int ai[3] = {i0, i1, i2};
        float bv[3] = {u0, u1, u2}; int bi[3] = {j0, j1, j2};
        float rv[3]; int ri[3];
        int p = 0, q = 0;
        #pragma unroll
        for (int t = 0; t < 3; t++) {
            bool ta = vi_lt(av[p], ai[p], bv[q], bi[q]);
            rv[t] = ta ? av[p] : bv[q];
            ri[t] = ta ? ai[p] : bi[q];
            p += ta ? 1 : 0; q += ta ? 0 : 1;
        }
        v0 = rv[0]; v1 = rv[1]; v2 = rv[2];
        i0 = ri[0]; i1 = ri[1]; i2 = ri[2];
    }

    if (lane == 0) {
        int base = row * TOPK;
        idxw[base + 0] = i0; idxw[base + 1] = i1; idxw[base + 2] = i2;
        out_idx[base + 0] = (float)i0;
        out_idx[base + 1] = (float)i1;
        out_idx[base + 2] = (float)i2;
        atomicAdd(&counts[i0], 1.0f);
        atomicAdd(&counts[i1], 1.0f);
        atomicAdd(&counts[i2], 1.0f);
        atomicAdd(&blk_loss, v0 + v1 + v2);   // LDS atomic, 4/block
    }
    __syncthreads();
    if (threadIdx.x == 0) loss_part[blockIdx.x] = blk_loss;
}

// -------------------------------------------- pure gather copy: quant = E[idx]
__global__ __launch_bounds__(256) void quant_copy_kernel(
    const int* __restrict__ idxw, const float* __restrict__ E,
    float* __restrict__ quant_out)
{
    int wave = threadIdx.x >> 6;
    int lane = threadIdx.x & 63;
    int j = blockIdx.x * 4 + wave;          // 0 .. N_ROWS*TOPK-1
    int code = idxw[j];
    float4 v = *(const float4*)&E[(size_t)code * DIM + lane * 4];
    *(float4*)&quant_out[(size_t)j * DIM + lane * 4] = v;
}

// ----------------------------------------- K-wise stage 1: avg_probs, sums
__global__ __launch_bounds__(256) void kstage1_kernel(
    const float* __restrict__ counts, const float* __restrict__ ecs,
    float* __restrict__ avgp, float* __restrict__ scalars)
{
    int k = blockIdx.x * 256 + threadIdx.x;
    float cnt = counts[k];
    float pr = ecs[k] * 0.99f + 0.01f * cnt;
    float p = cnt * (1.0f / (float)N_ROWS);
    avgp[k] = p;
    float ent = p * logf(p + 1e-10f);
    int lane = threadIdx.x & 63;
    #pragma unroll
    for (int off = 32; off; off >>= 1) {
        pr  += __shfl_down(pr, off);
        ent += __shfl_down(ent, off);
    }
    if (lane == 0) {
        atomicAdd(&scalars[0], pr);
        atomicAdd(&scalars[2], ent);
    }
}

// ------------------------- K-wise stage 2: normalized new_cs (recomputes pre)
__global__ __launch_bounds__(256) void kstage2_kernel(
    const float* __restrict__ counts, const float* __restrict__ ecs,
    const float* __restrict__ scalars, float* __restrict__ ncs)
{
    int k = blockIdx.x * 256 + threadIdx.x;
    float pre = ecs[k] * 0.99f + 0.01f * counts[k];
    float nt = scalars[0];
    ncs[k] = (pre + 1e-5f) / (nt + (float)KC * 1e-5f) * nt;
}

// ----------------------------------------- prefix scan of counts -> offsets
__global__ __launch_bounds__(1024) void scan_kernel(
    const float* __restrict__ counts, int* __restrict__ offsets)
{
    __shared__ int lds[1024];
    int t = threadIdx.x;
    int c[4]; int s = 0;
    #pragma unroll
    for (int q = 0; q < 4; q++) { c[q] = (int)(counts[t * 4 + q] + 0.5f); s += c[q]; }
    lds[t] = s;
    __syncthreads();
    for (int off = 1; off < 1024; off <<= 1) {
        int v = (t >= off) ? lds[t - off] : 0;
        __syncthreads();
        lds[t] += v;
        __syncthreads();
    }
    int base = lds[t] - s;   // exclusive prefix of this thread's chunk
    offsets[t * 4 + 0] = base;
    offsets[t * 4 + 1] = base + c[0];
    offsets[t * 4 + 2] = base + c[0] + c[1];
    offsets[t * 4 + 3] = base + c[0] + c[1] + c[2];
    if (t == 1023) offsets[4096] = lds[1023];
}

// -------------------- bucket fill: packed (code<<14 | row), grouped by code
__global__ __launch_bounds__(256) void bucket_fill_kernel(
    const int* __restrict__ idxw, const int* __restrict__ offsets,
    int* __restrict__ fill, int* __restrict__ bucket_list)
{
    int j = blockIdx.x * 256 + threadIdx.x;   // grid exact
    int code = idxw[j];
    int pos = atomicAdd(&fill[code], 1);
    bucket_list[offsets[code] + pos] = (code << 14) | (j / 3);
}

// -------------- balanced gather-accumulate: dw[code] += flat[row] over chunks
__global__ __launch_bounds__(256) void codeacc_kernel(
    const int* __restrict__ bl, const float* __restrict__ flat,
    float* __restrict__ dw)
{
    int wave = threadIdx.x >> 6;
    int lane = threadIdx.x & 63;
    int chunk = blockIdx.x * 4 + wave;        // 2048 chunks, grid exact
    int beg = chunk * CHUNK;

    int ent[CHUNK];
    #pragma unroll
    for (int q = 0; q < CHUNK; q++) ent[q] = bl[beg + q];

    float4 acc = {0.0f, 0.0f, 0.0f, 0.0f};
    int prev = ent[0] >> 14;
    #pragma unroll
    for (int q = 0; q < CHUNK; q++) {
        int code = ent[q] >> 14;
        int n    = ent[q] & 0x3fff;
        if (code != prev) {
            float* p = &dw[(size_t)prev * DIM + lane * 4];
            atomicAdd(p + 0, acc.x); atomicAdd(p + 1, acc.y);
            atomicAdd(p + 2, acc.z); atomicAdd(p + 3, acc.w);
            acc.x = acc.y = acc.z = acc.w = 0.0f;
            prev = code;
        }
        float4 v = *(const float4*)&flat[(size_t)n * DIM + lane * 4];
        acc.x += v.x; acc.y += v.y; acc.z += v.z; acc.w += v.w;
    }
    float* p = &dw[(size_t)prev * DIM + lane * 4];
    atomicAdd(p + 0, acc.x); atomicAdd(p + 1, acc.y);
    atomicAdd(p + 2, acc.z); atomicAdd(p + 3, acc.w);
}

// ------------- finalize: nemaw = 0.99*emaw + 0.01*dw ; upd = nemaw / ncs
__global__ __launch_bounds__(256) void finalize_kernel(
    const float* __restrict__ dw, const float* __restrict__ emaw,
    const float* __restrict__ ncs, float* __restrict__ nemaw,
    float* __restrict__ upd)
{
    int wave = threadIdx.x >> 6;
    int lane = threadIdx.x & 63;
    int k = blockIdx.x * 4 + wave;            // 1024 blocks, grid exact
    size_t o = (size_t)k * DIM + lane * 4;
    float4 d = *(const float4*)&dw[o];
    float4 w = *(const float4*)&emaw[o];
    float4 nm;
    nm.x = 0.99f * w.x + 0.01f * d.x;
    nm.y = 0.99f * w.y + 0.01f * d.y;
    nm.z = 0.99f * w.z + 0.01f * d.z;
    nm.w = 0.99f * w.w + 0.01f * d.w;
    *(float4*)&nemaw[o] = nm;
    float inv = ncs[k];
    float4 u = {nm.x / inv, nm.y / inv, nm.z / inv, nm.w / inv};
    *(float4*)&upd[o] = u;
}

// ------------------------------------------------------------- loss reduce
__global__ __launch_bounds__(1024) void loss_reduce_kernel(
    const float* __restrict__ lp, float* __restrict__ out)
{
    __shared__ float ls[16];
    int t = threadIdx.x;
    float s = lp[t] + lp[t + 1024] + lp[t + 2048] + lp[t + 3072];
    #pragma unroll
    for (int off = 32; off; off >>= 1) s += __shfl_down(s, off);
    if ((t & 63) == 0) ls[t >> 6] = s;
    __syncthreads();
    if (t == 0) {
        float tot = 0.0f;
        #pragma unroll
        for (int i = 0; i < 16; i++) tot += ls[i];
        out[O_LOSS] = 0.25f * tot / (float)(N_ROWS * TOPK * DIM);
    }
}

// ------------------------------------------------------------- perplexity
__global__ void final_kernel(const float* __restrict__ scalars, float* __restrict__ out)
{
    out[O_PERP] = expf(-scalars[2]);
}

extern "C" void kernel_launch(void* const* d_in, const int* in_sizes, int n_in,
                              void* d_out, int out_size, void* d_ws, size_t ws_size,
                              hipStream_t stream)
{
    const float* inputs = (const float*)d_in[0];   // [16,1024,256]
    const float* emb    = (const float*)d_in[1];   // [4096,256]
    const float* ecs    = (const float*)d_in[2];   // [4096]
    const float* emaw   = (const float*)d_in[3];   // [4096,256]
    float* out = (float*)d_out;
    char* ws = (char*)d_ws;

    int*   idxw        = (int*)ws;                  // 49152 ints
    int*   bucket_list = (int*)(ws + 196608);       // 49152 ints
    float* counts      = (float*)(ws + 393216);     // 4096 f
    int*   offsets     = (int*)(ws + 409600);       // 4097 ints
    int*   fill        = (int*)(ws + 430080);       // 4096 ints
    float* xn          = (float*)(ws + 446464);     // 16384 f
    float* en          = (float*)(ws + 512000);     // 4096 f
    float* scalars     = (float*)(ws + 528384);     // 8 f
    float* loss_part   = (float*)(ws + 528448);     // 4096 f

    // Scratch in the O_QUANT output region (free until quant_copy_kernel):
    // Aq: 16384x768 f16 = 6,291,456 floats @ out+4
    // Bq:  4096x768 f16 = 1,572,864 floats @ out+6,291,464
    // dw:  4096x256 f32 = 1,048,576 floats @ out+8,000,000 (ends 9,048,576)
    _Float16* Aq = (_Float16*)(out + 4);
    _Float16* Bq = (_Float16*)(out + 6291464);
    float*    dw = out + 8000000;

    hipMemsetAsync(counts, 0, KC * sizeof(float), stream);
    hipMemsetAsync(fill, 0, KC * sizeof(int), stream);
    hipMemsetAsync(scalars, 0, 8 * sizeof(float), stream);
    hipMemsetAsync(dw, 0, KC * DIM * sizeof(float), stream);

    // fp16 hi/lo split packs
    convert_kernel<<<N_ROWS / 4, 256, 0, stream>>>(inputs, Aq, 512, 256); // [hi|hi|lo]
    convert_kernel<<<KC / 4, 256, 0, stream>>>(emb, Bq, 256, 512);        // [hi|lo|hi]

    rownorm_kernel<<<N_ROWS / 4, 256, 0, stream>>>(inputs, xn, N_ROWS);
    rownorm_kernel<<<KC / 4, 256, 0, stream>>>(emb, en, KC);

    gemm_dist_kernel<<<(N_ROWS / 128) * (KC / 128), 256, 0, stream>>>(
        Aq, Bq, xn, en, out + O_DIST);

    top3_kernel<<<N_ROWS / 4, 256, 0, stream>>>(
        out + O_DIST, idxw, out + O_IDX, counts, loss_part);

    kstage1_kernel<<<KC / 256, 256, 0, stream>>>(counts, ecs, out + O_AVGP, scalars);
    kstage2_kernel<<<KC / 256, 256, 0, stream>>>(counts, ecs, scalars, out + O_NCS);
    scan_kernel<<<1, 1024, 0, stream>>>(counts, offsets);
    bucket_fill_kernel<<<(N_ROWS * TOPK) / 256, 256, 0, stream>>>(
        idxw, offsets, fill, bucket_list);

    codeacc_kernel<<<(TOTAL_E / CHUNK) / 4, 256, 0, stream>>>(
        bucket_list, inputs, dw);
    finalize_kernel<<<KC / 4, 256, 0, stream>>>(
        dw, emaw, out + O_NCS, out + O_NEMAW, out + O_UPD);

    quant_copy_kernel<<<(N_ROWS * TOPK) / 4, 256, 0, stream>>>(
        idxw, emb, out + O_QUANT);

    loss_reduce_kernel<<<1, 1024, 0, stream>>>(loss_part, out);
    final_kernel<<<1, 1, 0, stream>>>(scalars, out);
}